// Round 1
// baseline (187.058 us; speedup 1.0000x reference)
//
#include <hip/hip_runtime.h>
#include <hip/hip_bf16.h>

// DeepFM on MI355X. B=16384, NF=50, K=16, V=1e6, H=400, d=800.
// index = repeat(arange(B), NF) -> sample s owns rows [s*50, s*50+50).
//
// Pipeline (2 launches):
//   k1 prep:  blocks 0..607 transpose W0->W0t [512][800], W1->W1t [512][416]
//             (bf16, n-major, zero-padded); blocks 608..: per-sample first+
//             second order (fp32) -> fs.  x is NOT materialized anymore.
//   k2 fused: one block per 64-sample panel, 512 threads (8 waves, 2Mx4N):
//             phase 1: h0 = relu(emb-gather @ W0t + b0) -> LDS panel
//                      [64][424] bf16 (A gathered direct from f32 embedding
//                      via sfeat LDS index cache, cvt to bf16 in-register;
//                      no x buffer, no A staging)
//             phase 2: h1 = relu(h0 @ W1t + b1), dot W2, cross-wave reduce
//             final:   out = sigmoid(fs + relu(sum + b2))
//             B staged via global_load_lds width=16, 448 cols (not 512 -> 
//             -12.5% MFMA), single-plane double buffer, ONE barrier/plane
//             (stage p+1 + A-prefetch p+1 issued before compute p).

#define BATCH 16384
#define NFLD  50
#define EK    16
#define DDIM  800   // NF*K  (= gemm1 K, exact, 25 planes)
#define HDIM  400
#define HPAD  416   // HDIM padded to mult of 32 (= gemm2 K, 13 planes)
#define NPAD  512   // W0t/W1t allocated rows

#define TB_W0 400            // 25 k-tiles x 16 n-tiles for W0 transpose
#define TB_W1 208            // 13 k-tiles x 16 n-tiles for W1 transpose
#define TBLK  (TB_W0 + TB_W1)
#define GBLK  (BATCH / 16)   // gather blocks: 16 samples/block (4 per wave)

#define MROWS 64             // samples per fused block
#define NCOLS 448            // gemm n-cols computed (>= HPAD, 28x16)
#define WCOLS 112            // n-cols per waveN
#define NFRAG 7              // 16-col frags per wave
#define P1    (DDIM / 32)    // 25 K-planes, phase 1
#define P2    (HPAD / 32)    // 13 K-planes, phase 2
#define H0S   424            // h0 LDS panel stride (bf16): 848B, 16B-aligned,
                             // rows land on 8 distinct bank groups -> 2-way (free)
#define NCHUNK (NCOLS / 16)  // 28 staging chunks per plane

typedef __attribute__((ext_vector_type(8))) __bf16 bf16x8;
typedef __attribute__((ext_vector_type(4))) float  f32x4;

typedef const __attribute__((address_space(1))) unsigned int* gas_u32p;
typedef __attribute__((address_space(3))) unsigned int*       las_u32p;

__device__ __forceinline__ void gld_lds16(const void* g, void* l) {
    // async global->LDS, 16B/lane; HW dest = wave-uniform base + lane*16.
    __builtin_amdgcn_global_load_lds((gas_u32p)g, (las_u32p)l, 16, 0, 0);
}

__device__ __forceinline__ bf16x8 cvt8(const float4 a, const float4 b) {
    union { __hip_bfloat16 h[8]; bf16x8 v; } u;
    u.h[0] = __float2bfloat16(a.x); u.h[1] = __float2bfloat16(a.y);
    u.h[2] = __float2bfloat16(a.z); u.h[3] = __float2bfloat16(a.w);
    u.h[4] = __float2bfloat16(b.x); u.h[5] = __float2bfloat16(b.y);
    u.h[6] = __float2bfloat16(b.z); u.h[7] = __float2bfloat16(b.w);
    return u.v;
}

// ---------------- k1: transpose (blocks < TBLK) + first/second order ----------
__global__ __launch_bounds__(256) void prep_kernel(
    const float* __restrict__ W0, const float* __restrict__ W1,
    __hip_bfloat16* __restrict__ W0t, __hip_bfloat16* __restrict__ W1t,
    const int* __restrict__ feats, const float* __restrict__ values,
    const float* __restrict__ biasp, const float* __restrict__ weights,
    const float* __restrict__ embedding, float* __restrict__ fs)
{
    const int bid = blockIdx.x;
    if (bid < TBLK) {
        // ---- tiled transpose f32 -> bf16 with zero pad ----
        const int which = bid >= TB_W0;
        const int i  = which ? bid - TB_W0 : bid;
        const int nx = which ? 13 : 25;                  // k-tiles
        const int bx = i % nx, by = i / nx;
        const float* src = which ? W1 : W0;
        __hip_bfloat16* dst = which ? W1t : W0t;
        const int srcK = which ? HDIM : DDIM;            // source rows (k)
        const int dstCols = which ? HPAD : DDIM;

        __shared__ float tile[32][33];
        const int tx = threadIdx.x & 31, ty = threadIdx.x >> 5;   // 32 x 8
        const int k0 = bx * 32, n0 = by * 32;
#pragma unroll
        for (int r = 0; r < 4; ++r) {
            int k = k0 + ty + r * 8;
            int n = n0 + tx;
            float v = (k < srcK && n < HDIM) ? src[(long)k * HDIM + n] : 0.f;
            tile[ty + r * 8][tx] = v;
        }
        __syncthreads();
#pragma unroll
        for (int r = 0; r < 4; ++r) {
            int n = n0 + ty + r * 8;   // dst row
            int k = k0 + tx;           // dst col
            if (k < dstCols)
                dst[(long)n * dstCols + k] = __float2bfloat16(tile[tx][ty + r * 8]);
        }
        return;
    }

    // ---- first/second order: 4 samples per wave ----
    const int wave = threadIdx.x >> 6;
    const int lane = threadIdx.x & 63;
    const int r    = lane >> 2, c = lane & 3;
    const int sbase = (bid - TBLK) * 16 + wave * 4;

    int   f[4] = {0, 0, 0, 0};
    float v[4] = {0.f, 0.f, 0.f, 0.f};
    float wsum[4] = {0.f, 0.f, 0.f, 0.f};
#pragma unroll
    for (int q = 0; q < 4; ++q) {
        const long base = (long)(sbase + q) * NFLD;
        if (lane < NFLD) {
            f[q] = feats[base + lane];
            v[q] = values[base + lane];
            wsum[q] = weights[f[q]] * v[q];
        }
    }

    // broadcast all indices, then fire all 16 gathers back-to-back (MLP)
    int   fj[4][4]; float vj[4][4];
#pragma unroll
    for (int q = 0; q < 4; ++q)
#pragma unroll
        for (int p = 0; p < 4; ++p) {
            const int j = p * 16 + r;
            if (p < 3 || r < 2) {
                fj[q][p] = __shfl(f[q], j);
                vj[q][p] = __shfl(v[q], j);
            }
        }
    float4 e[4][4];
#pragma unroll
    for (int q = 0; q < 4; ++q)
#pragma unroll
        for (int p = 0; p < 4; ++p)
            if (p < 3 || r < 2)
                e[q][p] = *(const float4*)(embedding + (long)fj[q][p] * EK + c * 4);

#pragma unroll
    for (int q = 0; q < 4; ++q) {
        const int s = sbase + q;
        f32x4 s1 = {0.f, 0.f, 0.f, 0.f}, s2 = {0.f, 0.f, 0.f, 0.f};
#pragma unroll
        for (int p = 0; p < 4; ++p) {
            const int j = p * 16 + r;
            if (p < 3 || r < 2) {                 // j < 50
                f32x4 ef = {e[q][p].x, e[q][p].y, e[q][p].z, e[q][p].w};
                f32x4 ev = ef * vj[q][p];
                s1 += ev;
                s2 += ev * ev;
            }
        }
#pragma unroll
        for (int m = 4; m <= 32; m <<= 1) {
            s1.x += __shfl_xor(s1.x, m); s1.y += __shfl_xor(s1.y, m);
            s1.z += __shfl_xor(s1.z, m); s1.w += __shfl_xor(s1.w, m);
            s2.x += __shfl_xor(s2.x, m); s2.y += __shfl_xor(s2.y, m);
            s2.z += __shfl_xor(s2.z, m); s2.w += __shfl_xor(s2.w, m);
        }
        float t = (s1.x * s1.x - s2.x) + (s1.y * s1.y - s2.y)
                + (s1.z * s1.z - s2.z) + (s1.w * s1.w - s2.w);
        t += __shfl_xor(t, 1); t += __shfl_xor(t, 2);
        float w = wsum[q];
        w += __shfl_xor(w, 1);  w += __shfl_xor(w, 2);
        w += __shfl_xor(w, 4);  w += __shfl_xor(w, 8);
        w += __shfl_xor(w, 16); w += __shfl_xor(w, 32);
        if (lane == 0) fs[s] = w + 0.5f * t + biasp[0];
    }
}

// ---------------- k2: fused gather-GEMM1-GEMM2-final ----------------
// 64-row panel per block; 8 waves (2M x 4N); per-wave tile 32 x 112 (2x7 frags).
__global__ __launch_bounds__(512, 2) void fused_mlp_kernel(
    const int* __restrict__ feats, const float* __restrict__ embedding,
    const __hip_bfloat16* __restrict__ W0t, const __hip_bfloat16* __restrict__ W1t,
    const float* __restrict__ b0p, const float* __restrict__ b1p,
    const float* __restrict__ W2, const float* __restrict__ b2p,
    const float* __restrict__ fs, float* __restrict__ out)
{
    __shared__ __align__(16) __hip_bfloat16 sB[2][NCOLS * 32];   // 56 KB
    __shared__ __align__(16) __hip_bfloat16 h0p[MROWS * H0S];    // 53 KB
    __shared__ int   sfeat[MROWS * NFLD];                        // 12.5 KB
    __shared__ float red[MROWS][4];                              // 1 KB

    const int tid  = threadIdx.x;
    const int wave = tid >> 6, lane = tid & 63;
    const int l16  = lane & 15, quad = lane >> 4;
    const int waveM = wave & 1, waveN = wave >> 1;
    const int m0 = blockIdx.x * MROWS;

    // feat index cache for this panel's 64 samples
    for (int i = tid; i < MROWS * NFLD; i += 512)
        sfeat[i] = feats[(long)m0 * NFLD + i];

    const float b0 = b0p[0];
    const float b1 = b1p[0];

    // B staging: chunk = 16 rows x 32 cols = 1KB; lane -> row +(lane>>2),
    // col (lane&3)*8.  28 chunks over 8 waves.
    auto stageB = [&](const __hip_bfloat16* Bt, int ldb, int k0, int h) {
#pragma unroll
        for (int c = 0; c < 4; ++c) {
            const int ch = wave + c * 8;             // wave-uniform predicate
            if (ch < NCHUNK) {
                const __hip_bfloat16* src =
                    Bt + (long)(ch * 16 + (lane >> 2)) * ldb + k0 + (lane & 3) * 8;
                gld_lds16(src, &sB[h][ch * 512 + lane * 8]);
            }
        }
    };

    // A prefetch for plane p: af rows = waveM*32 + i*16 + l16;
    // col k = p*32 + quad*8 -> field f = 2p + (quad>>1), dim d0 = (quad&1)*8.
    auto loadA = [&](int p, float4* rg) {
        const int f  = p * 2 + (quad >> 1);
        const int d0 = (quad & 1) * 8;
#pragma unroll
        for (int i = 0; i < 2; ++i) {
            const int row = waveM * 32 + i * 16 + l16;
            const long fi = sfeat[row * NFLD + f];
            const float* ep = embedding + fi * EK + d0;
            rg[2 * i]     = *(const float4*)ep;
            rg[2 * i + 1] = *(const float4*)(ep + 4);
        }
    };

    // ---------------- phase 1: h0 = relu(emb @ W0t + b0) ----------------
    f32x4 acc[2][NFRAG] = {};

    __syncthreads();                    // sfeat visible
    float4 ra[4];
    loadA(0, ra);
    stageB(W0t, DDIM, 0, 0);
    __syncthreads();                    // plane-0 A regs + B staged

#pragma unroll
    for (int p = 0; p < P1; ++p) {
        const int h = p & 1;
        float4 rn[4];
        if (p + 1 < P1) {               // issue next plane's loads FIRST
            stageB(W0t, DDIM, (p + 1) * 32, h ^ 1);
            loadA(p + 1, rn);
        }
        bf16x8 af[2];
        af[0] = cvt8(ra[0], ra[1]);
        af[1] = cvt8(ra[2], ra[3]);
        bf16x8 bfr[NFRAG];
#pragma unroll
        for (int j = 0; j < NFRAG; ++j)
            bfr[j] = *(const bf16x8*)&sB[h][(waveN * WCOLS + j * 16 + l16) * 32 + quad * 8];
#pragma unroll
        for (int i = 0; i < 2; ++i)
#pragma unroll
            for (int j = 0; j < NFRAG; ++j)
                acc[i][j] = __builtin_amdgcn_mfma_f32_16x16x32_bf16(
                    af[i], bfr[j], acc[i][j], 0, 0, 0);
        __syncthreads();                // drains stage+loadA; guards sB reuse
        if (p + 1 < P1) {
#pragma unroll
            for (int q = 0; q < 4; ++q) ra[q] = rn[q];
        }
    }

    // write h0 panel to LDS (bf16), relu+b0, cols [400,416) -> 0, >=416 skip
#pragma unroll
    for (int i = 0; i < 2; ++i)
#pragma unroll
        for (int j = 0; j < NFRAG; ++j) {
            const int col = waveN * WCOLS + j * 16 + l16;
            if (col < HPAD) {
#pragma unroll
                for (int r = 0; r < 4; ++r) {
                    const int row = waveM * 32 + i * 16 + quad * 4 + r;
                    float v = acc[i][j][r] + b0;
                    v = v > 0.f ? v : 0.f;
                    if (col >= HDIM) v = 0.f;
                    h0p[row * H0S + col] = __float2bfloat16(v);
                }
            }
        }

    // ---------------- phase 2: h1 = relu(h0 @ W1t + b1), dot W2 ----------------
    f32x4 acc2[2][NFRAG] = {};
    stageB(W1t, HPAD, 0, 0);            // safe: phase-1 sB reads done (last barrier)
    float w2v[NFRAG];
#pragma unroll
    for (int j = 0; j < NFRAG; ++j) {
        const int col = waveN * WCOLS + j * 16 + l16;
        w2v[j] = (col < HDIM) ? W2[col] : 0.f;
    }
    __syncthreads();                    // h0p writes + stage(0) drained

#pragma unroll
    for (int p = 0; p < P2; ++p) {
        const int h = p & 1;
        if (p + 1 < P2)
            stageB(W1t, HPAD, (p + 1) * 32, h ^ 1);
        bf16x8 af[2];
#pragma unroll
        for (int i = 0; i < 2; ++i)
            af[i] = *(const bf16x8*)&h0p[(waveM * 32 + i * 16 + l16) * H0S + p * 32 + quad * 8];
        bf16x8 bfr[NFRAG];
#pragma unroll
        for (int j = 0; j < NFRAG; ++j)
            bfr[j] = *(const bf16x8*)&sB[h][(waveN * WCOLS + j * 16 + l16) * 32 + quad * 8];
#pragma unroll
        for (int i = 0; i < 2; ++i)
#pragma unroll
            for (int j = 0; j < NFRAG; ++j)
                acc2[i][j] = __builtin_amdgcn_mfma_f32_16x16x32_bf16(
                    af[i], bfr[j], acc2[i][j], 0, 0, 0);
        __syncthreads();
    }

    // per-row partial: relu(acc2 + b1) . W2, reduce over l16, then cross-wave
#pragma unroll
    for (int i = 0; i < 2; ++i)
#pragma unroll
        for (int r = 0; r < 4; ++r) {
            float ps = 0.f;
#pragma unroll
            for (int j = 0; j < NFRAG; ++j) {
                float v = acc2[i][j][r] + b1;
                v = v > 0.f ? v : 0.f;
                ps += v * w2v[j];
            }
            ps += __shfl_xor(ps, 1); ps += __shfl_xor(ps, 2);
            ps += __shfl_xor(ps, 4); ps += __shfl_xor(ps, 8);
            if (l16 == 0)
                red[waveM * 32 + i * 16 + quad * 4 + r][waveN] = ps;
        }
    __syncthreads();

    if (tid < MROWS) {
        const float s = (red[tid][0] + red[tid][1]) + (red[tid][2] + red[tid][3]);
        float hv = s + b2p[0];
        hv = hv > 0.f ? hv : 0.f;
        const float z = fs[m0 + tid] + hv;
        out[m0 + tid] = 1.f / (1.f + __expf(-z));
    }
}

extern "C" void kernel_launch(void* const* d_in, const int* in_sizes, int n_in,
                              void* d_out, int out_size, void* d_ws, size_t ws_size,
                              hipStream_t stream)
{
    // 0 index, 1 feats, 2 values, 3 bias, 4 weights, 5 embedding,
    // 6 W0, 7 b0, 8 W1, 9 b1, 10 W2, 11 b2, 12 batch_size
    const int*   feats     = (const int*)d_in[1];
    const float* values    = (const float*)d_in[2];
    const float* bias      = (const float*)d_in[3];
    const float* weights   = (const float*)d_in[4];
    const float* embedding = (const float*)d_in[5];
    const float* W0 = (const float*)d_in[6];
    const float* b0 = (const float*)d_in[7];
    const float* W1 = (const float*)d_in[8];
    const float* b1 = (const float*)d_in[9];
    const float* W2 = (const float*)d_in[10];
    const float* b2 = (const float*)d_in[11];

    char* ws = (char*)d_ws;
    size_t off = 0;
    auto alloc = [&](size_t bytes) {
        void* p = ws + off;
        off += (bytes + 255) & ~(size_t)255;
        return p;
    };
    float*          fs   = (float*)alloc((size_t)BATCH * 4);
    __hip_bfloat16* W0t  = (__hip_bfloat16*)alloc((size_t)NPAD * DDIM * 2);
    __hip_bfloat16* W1t  = (__hip_bfloat16*)alloc((size_t)NPAD * HPAD * 2);
    (void)ws_size; (void)in_sizes; (void)n_in; (void)out_size;

    prep_kernel<<<dim3(TBLK + GBLK), 256, 0, stream>>>(
        W0, W1, W0t, W1t, feats, values, bias, weights, embedding, fs);
    fused_mlp_kernel<<<dim3(BATCH / MROWS), 512, 0, stream>>>(
        feats, embedding, W0t, W1t, b0, b1, W2, b2, fs, (float*)d_out);
}

// Round 2
// 181.066 us; speedup vs baseline: 1.0331x; 1.0331x over previous
//
#include <hip/hip_runtime.h>
#include <hip/hip_bf16.h>

// DeepFM on MI355X. B=16384, NF=50, K=16, V=1e6, H=400, d=800.
// index = repeat(arange(B), NF) -> sample s owns rows [s*50, s*50+50).
//
// Pipeline (2 launches):
//   k1 prep:  blocks 0..607 transpose W0->W0t [512][800], W1->W1t [512][416]
//             (bf16, n-major, zero-padded); blocks 608..: per-sample first+
//             second order (fp32) -> fs, AND emb -> x bf16 [16384][800].
//             Gather lives HERE (high occupancy, 16 row-loads in flight/wave,
//             latency hidden by TLP) — R1 showed in-GEMM gather is latency-
//             bound (989 GB/s, MfmaUtil 11%).
//   k2 fused: one block per 64-sample panel, 512 threads (8 waves, 2Mx4N):
//             phase 1: h0 = relu(x @ W0t + b0) -> LDS panel [64][424] bf16
//                      (A staged linearly from x via global_load_lds)
//             phase 2: h1 = relu(h0 @ W1t + b1), dot W2, cross-wave reduce
//             final:   out = sigmoid(fs + relu(sum + b2))
//             h0 / h1 / partial never touch HBM. BK=64 = two 32-planes per
//             barrier pair (round-0 proven structure), N=448 (-12.5% MFMA
//             vs 512-pad). LDS ~118 KB -> 1 block/CU, 256 blocks = 1 sweep.

#define BATCH 16384
#define NFLD  50
#define EK    16
#define DDIM  800   // NF*K  (= gemm1 K, exact, 25 planes)
#define HDIM  400
#define HPAD  416   // HDIM padded to mult of 32 (= gemm2 K, 13 planes)
#define NPAD  512   // W0t/W1t allocated rows

#define TB_W0 400            // 25 k-tiles x 16 n-tiles for W0 transpose
#define TB_W1 208            // 13 k-tiles x 16 n-tiles for W1 transpose
#define TBLK  (TB_W0 + TB_W1)
#define GBLK  (BATCH / 16)   // gather blocks: 16 samples/block (4 per wave)

#define MROWS 64             // samples per fused block
#define NCOLS 448            // gemm n-cols computed (>= HPAD, 28x16)
#define WCOLS 112            // n-cols per waveN
#define NFRAG 7              // 16-col frags per wave
#define P1    (DDIM / 32)    // 25 K-planes, phase 1
#define P2    (HPAD / 32)    // 13 K-planes, phase 2
#define H0S   424            // h0 LDS panel stride (bf16): 848B, 16B-aligned
#define NCHUNK (NCOLS / 16)  // 28 B-staging chunks per plane

typedef __attribute__((ext_vector_type(8))) __bf16 bf16x8;
typedef __attribute__((ext_vector_type(4))) float  f32x4;

typedef const __attribute__((address_space(1))) unsigned int* gas_u32p;
typedef __attribute__((address_space(3))) unsigned int*       las_u32p;

__device__ __forceinline__ void gld_lds16(const void* g, void* l) {
    // async global->LDS, 16B/lane; HW dest = wave-uniform base + lane*16.
    __builtin_amdgcn_global_load_lds((gas_u32p)g, (las_u32p)l, 16, 0, 0);
}

// ---------------- k1: transpose (blocks < TBLK) + gather ----------------
__global__ __launch_bounds__(256) void prep_kernel(
    const float* __restrict__ W0, const float* __restrict__ W1,
    __hip_bfloat16* __restrict__ W0t, __hip_bfloat16* __restrict__ W1t,
    const int* __restrict__ feats, const float* __restrict__ values,
    const float* __restrict__ biasp, const float* __restrict__ weights,
    const float* __restrict__ embedding,
    float* __restrict__ fs, __hip_bfloat16* __restrict__ x)
{
    const int bid = blockIdx.x;
    if (bid < TBLK) {
        // ---- tiled transpose f32 -> bf16 with zero pad ----
        const int which = bid >= TB_W0;
        const int i  = which ? bid - TB_W0 : bid;
        const int nx = which ? 13 : 25;                  // k-tiles
        const int bx = i % nx, by = i / nx;
        const float* src = which ? W1 : W0;
        __hip_bfloat16* dst = which ? W1t : W0t;
        const int srcK = which ? HDIM : DDIM;            // source rows (k)
        const int dstCols = which ? HPAD : DDIM;

        __shared__ float tile[32][33];
        const int tx = threadIdx.x & 31, ty = threadIdx.x >> 5;   // 32 x 8
        const int k0 = bx * 32, n0 = by * 32;
#pragma unroll
        for (int r = 0; r < 4; ++r) {
            int k = k0 + ty + r * 8;
            int n = n0 + tx;
            float v = (k < srcK && n < HDIM) ? src[(long)k * HDIM + n] : 0.f;
            tile[ty + r * 8][tx] = v;
        }
        __syncthreads();
#pragma unroll
        for (int r = 0; r < 4; ++r) {
            int n = n0 + ty + r * 8;   // dst row
            int k = k0 + tx;           // dst col
            if (k < dstCols)
                dst[(long)n * dstCols + k] = __float2bfloat16(tile[tx][ty + r * 8]);
        }
        return;
    }

    // ---- gather + first/second order: 4 samples per wave ----
    const int wave = threadIdx.x >> 6;
    const int lane = threadIdx.x & 63;
    const int r    = lane >> 2, c = lane & 3;
    const int sbase = (bid - TBLK) * 16 + wave * 4;

    int   f[4] = {0, 0, 0, 0};
    float v[4] = {0.f, 0.f, 0.f, 0.f};
    float wsum[4] = {0.f, 0.f, 0.f, 0.f};
#pragma unroll
    for (int q = 0; q < 4; ++q) {
        const long base = (long)(sbase + q) * NFLD;
        if (lane < NFLD) {
            f[q] = feats[base + lane];
            v[q] = values[base + lane];
            wsum[q] = weights[f[q]] * v[q];
        }
    }

    // broadcast all indices, then fire all 16 gathers back-to-back (MLP)
    int   fj[4][4]; float vj[4][4];
#pragma unroll
    for (int q = 0; q < 4; ++q)
#pragma unroll
        for (int p = 0; p < 4; ++p) {
            const int j = p * 16 + r;
            if (p < 3 || r < 2) {
                fj[q][p] = __shfl(f[q], j);
                vj[q][p] = __shfl(v[q], j);
            }
        }
    float4 e[4][4];
#pragma unroll
    for (int q = 0; q < 4; ++q)
#pragma unroll
        for (int p = 0; p < 4; ++p)
            if (p < 3 || r < 2)
                e[q][p] = *(const float4*)(embedding + (long)fj[q][p] * EK + c * 4);

#pragma unroll
    for (int q = 0; q < 4; ++q) {
        const int s = sbase + q;
        f32x4 s1 = {0.f, 0.f, 0.f, 0.f}, s2 = {0.f, 0.f, 0.f, 0.f};
#pragma unroll
        for (int p = 0; p < 4; ++p) {
            const int j = p * 16 + r;
            if (p < 3 || r < 2) {                 // j < 50
                f32x4 ef = {e[q][p].x, e[q][p].y, e[q][p].z, e[q][p].w};
                f32x4 ev = ef * vj[q][p];
                s1 += ev;
                s2 += ev * ev;
                __hip_bfloat16 pk[4] = {
                    __float2bfloat16(e[q][p].x), __float2bfloat16(e[q][p].y),
                    __float2bfloat16(e[q][p].z), __float2bfloat16(e[q][p].w)};
                *(uint2*)&x[(long)s * DDIM + j * EK + c * 4] = *(uint2*)pk;
            }
        }
#pragma unroll
        for (int m = 4; m <= 32; m <<= 1) {
            s1.x += __shfl_xor(s1.x, m); s1.y += __shfl_xor(s1.y, m);
            s1.z += __shfl_xor(s1.z, m); s1.w += __shfl_xor(s1.w, m);
            s2.x += __shfl_xor(s2.x, m); s2.y += __shfl_xor(s2.y, m);
            s2.z += __shfl_xor(s2.z, m); s2.w += __shfl_xor(s2.w, m);
        }
        float t = (s1.x * s1.x - s2.x) + (s1.y * s1.y - s2.y)
                + (s1.z * s1.z - s2.z) + (s1.w * s1.w - s2.w);
        t += __shfl_xor(t, 1); t += __shfl_xor(t, 2);
        float w = wsum[q];
        w += __shfl_xor(w, 1);  w += __shfl_xor(w, 2);
        w += __shfl_xor(w, 4);  w += __shfl_xor(w, 8);
        w += __shfl_xor(w, 16); w += __shfl_xor(w, 32);
        if (lane == 0) fs[s] = w + 0.5f * t + biasp[0];
    }
}

// ---------------- k2: fused GEMM1 -> LDS h0 -> GEMM2 -> final ----------------
// 64-row panel per block; 8 waves (2M x 4N); per-wave tile 32 x 112 (2x7 frags).
__global__ __launch_bounds__(512, 2) void fused_mlp_kernel(
    const __hip_bfloat16* __restrict__ x,
    const __hip_bfloat16* __restrict__ W0t, const __hip_bfloat16* __restrict__ W1t,
    const float* __restrict__ b0p, const float* __restrict__ b1p,
    const float* __restrict__ W2, const float* __restrict__ b2p,
    const float* __restrict__ fs, float* __restrict__ out)
{
    __shared__ __align__(16) __hip_bfloat16 sA[2][MROWS * 32];   // 8 KB
    __shared__ __align__(16) __hip_bfloat16 sB[2][NCOLS * 32];   // 56 KB
    __shared__ __align__(16) __hip_bfloat16 h0p[MROWS * H0S];    // 53 KB
    __shared__ float red[MROWS][4];                              // 1 KB

    const int tid  = threadIdx.x;
    const int wave = tid >> 6, lane = tid & 63;
    const int l16  = lane & 15, quad = lane >> 4;
    const int waveM = wave & 1, waveN = wave >> 1;
    const int m0 = blockIdx.x * MROWS;
    const int rlane = lane >> 2, clane = (lane & 3) * 8;   // 16x32 chunk layout

    const float b0 = b0p[0];
    const float b1 = b1p[0];

    // phase-1 staging: 32 chunks (A: 4 of x-panel, B: 28 of W0t), 4 per wave
    auto stage1 = [&](int p, int h) {
        const int k0 = p * 32;
#pragma unroll
        for (int c = 0; c < 4; ++c) {
            const int idx = wave * 4 + c;              // wave-uniform
            if (idx < 4) {
                gld_lds16(x + (long)(m0 + idx * 16 + rlane) * DDIM + k0 + clane,
                          &sA[h][idx * 512 + lane * 8]);
            } else {
                const int ch = idx - 4;
                gld_lds16(W0t + (long)(ch * 16 + rlane) * DDIM + k0 + clane,
                          &sB[h][ch * 512 + lane * 8]);
            }
        }
    };
    // phase-2 staging: B only (28 chunks of W1t)
    auto stage2 = [&](int p, int h) {
        const int k0 = p * 32;
#pragma unroll
        for (int c = 0; c < 4; ++c) {
            const int ch = wave + c * 8;               // wave-uniform
            if (ch < NCHUNK) {
                gld_lds16(W1t + (long)(ch * 16 + rlane) * HPAD + k0 + clane,
                          &sB[h][ch * 512 + lane * 8]);
            }
        }
    };

    // ---------------- phase 1: h0 = relu(x @ W0t + b0) ----------------
    f32x4 acc[2][NFRAG] = {};
    auto compute1 = [&](int h) {
        bf16x8 af[2], bfr[NFRAG];
#pragma unroll
        for (int i = 0; i < 2; ++i)
            af[i] = *(const bf16x8*)&sA[h][(waveM * 32 + i * 16 + l16) * 32 + quad * 8];
#pragma unroll
        for (int j = 0; j < NFRAG; ++j)
            bfr[j] = *(const bf16x8*)&sB[h][(waveN * WCOLS + j * 16 + l16) * 32 + quad * 8];
#pragma unroll
        for (int i = 0; i < 2; ++i)
#pragma unroll
            for (int j = 0; j < NFRAG; ++j)
                acc[i][j] = __builtin_amdgcn_mfma_f32_16x16x32_bf16(
                    af[i], bfr[j], acc[i][j], 0, 0, 0);
    };

    for (int kt = 0; kt + 1 < P1; kt += 2) {
        stage1(kt, 0); stage1(kt + 1, 1);
        __syncthreads();                 // compiler drains vmcnt before barrier
        compute1(0); compute1(1);
        __syncthreads();
    }
    // P1 = 25 is odd: one-plane tail
    stage1(P1 - 1, 0);
    __syncthreads();
    compute1(0);
    __syncthreads();

    // write h0 panel to LDS (bf16), relu+b0; cols [400,416) -> 0; >=416 skip
#pragma unroll
    for (int i = 0; i < 2; ++i)
#pragma unroll
        for (int j = 0; j < NFRAG; ++j) {
            const int col = waveN * WCOLS + j * 16 + l16;
            if (col < HPAD) {
#pragma unroll
                for (int r = 0; r < 4; ++r) {
                    const int row = waveM * 32 + i * 16 + quad * 4 + r;
                    float v = acc[i][j][r] + b0;
                    v = v > 0.f ? v : 0.f;
                    if (col >= HDIM) v = 0.f;
                    h0p[row * H0S + col] = __float2bfloat16(v);
                }
            }
        }

    // ---------------- phase 2: h1 = relu(h0 @ W1t + b1), dot W2 ----------------
    f32x4 acc2[2][NFRAG] = {};
    float w2v[NFRAG];
#pragma unroll
    for (int j = 0; j < NFRAG; ++j) {
        const int col = waveN * WCOLS + j * 16 + l16;
        w2v[j] = (col < HDIM) ? W2[col] : 0.f;
    }
    auto compute2 = [&](int h, int p) {
        bf16x8 af[2], bfr[NFRAG];
#pragma unroll
        for (int i = 0; i < 2; ++i)
            af[i] = *(const bf16x8*)&h0p[(waveM * 32 + i * 16 + l16) * H0S + p * 32 + quad * 8];
#pragma unroll
        for (int j = 0; j < NFRAG; ++j)
            bfr[j] = *(const bf16x8*)&sB[h][(waveN * WCOLS + j * 16 + l16) * 32 + quad * 8];
#pragma unroll
        for (int i = 0; i < 2; ++i)
#pragma unroll
            for (int j = 0; j < NFRAG; ++j)
                acc2[i][j] = __builtin_amdgcn_mfma_f32_16x16x32_bf16(
                    af[i], bfr[j], acc2[i][j], 0, 0, 0);
    };

    for (int kt = 0; kt + 1 < P2; kt += 2) {
        stage2(kt, 0); stage2(kt + 1, 1);
        __syncthreads();                 // 1st iter: also publishes h0p writes
        compute2(0, kt); compute2(1, kt + 1);
        __syncthreads();
    }
    // P2 = 13 is odd: one-plane tail
    stage2(P2 - 1, 0);
    __syncthreads();
    compute2(0, P2 - 1);

    // per-row partial: relu(acc2 + b1) . W2, reduce over l16, then cross-wave
#pragma unroll
    for (int i = 0; i < 2; ++i)
#pragma unroll
        for (int r = 0; r < 4; ++r) {
            float ps = 0.f;
#pragma unroll
            for (int j = 0; j < NFRAG; ++j) {
                float v = acc2[i][j][r] + b1;
                v = v > 0.f ? v : 0.f;
                ps += v * w2v[j];
            }
            ps += __shfl_xor(ps, 1); ps += __shfl_xor(ps, 2);
            ps += __shfl_xor(ps, 4); ps += __shfl_xor(ps, 8);
            if (l16 == 0)
                red[waveM * 32 + i * 16 + quad * 4 + r][waveN] = ps;
        }
    __syncthreads();

    if (tid < MROWS) {
        const float s = (red[tid][0] + red[tid][1]) + (red[tid][2] + red[tid][3]);
        float hv = s + b2p[0];
        hv = hv > 0.f ? hv : 0.f;
        const float z = fs[m0 + tid] + hv;
        out[m0 + tid] = 1.f / (1.f + __expf(-z));
    }
}

extern "C" void kernel_launch(void* const* d_in, const int* in_sizes, int n_in,
                              void* d_out, int out_size, void* d_ws, size_t ws_size,
                              hipStream_t stream)
{
    // 0 index, 1 feats, 2 values, 3 bias, 4 weights, 5 embedding,
    // 6 W0, 7 b0, 8 W1, 9 b1, 10 W2, 11 b2, 12 batch_size
    const int*   feats     = (const int*)d_in[1];
    const float* values    = (const float*)d_in[2];
    const float* bias      = (const float*)d_in[3];
    const float* weights   = (const float*)d_in[4];
    const float* embedding = (const float*)d_in[5];
    const float* W0 = (const float*)d_in[6];
    const float* b0 = (const float*)d_in[7];
    const float* W1 = (const float*)d_in[8];
    const float* b1 = (const float*)d_in[9];
    const float* W2 = (const float*)d_in[10];
    const float* b2 = (const float*)d_in[11];

    char* ws = (char*)d_ws;
    size_t off = 0;
    auto alloc = [&](size_t bytes) {
        void* p = ws + off;
        off += (bytes + 255) & ~(size_t)255;
        return p;
    };
    float*          fs   = (float*)alloc((size_t)BATCH * 4);
    __hip_bfloat16* x    = (__hip_bfloat16*)alloc((size_t)BATCH * DDIM * 2);
    __hip_bfloat16* W0t  = (__hip_bfloat16*)alloc((size_t)NPAD * DDIM * 2);
    __hip_bfloat16* W1t  = (__hip_bfloat16*)alloc((size_t)NPAD * HPAD * 2);
    (void)ws_size; (void)in_sizes; (void)n_in; (void)out_size;

    prep_kernel<<<dim3(TBLK + GBLK), 256, 0, stream>>>(
        W0, W1, W0t, W1t, feats, values, bias, weights, embedding, fs, x);
    fused_mlp_kernel<<<dim3(BATCH / MROWS), 512, 0, stream>>>(
        x, W0t, W1t, b0, b1, W2, b2, fs, (float*)d_out);
}

// Round 4
// 178.052 us; speedup vs baseline: 1.0506x; 1.0169x over previous
//
#include <hip/hip_runtime.h>
#include <hip/hip_bf16.h>

// DeepFM on MI355X. B=16384, NF=50, K=16, V=1e6, H=400, d=800.
// index = repeat(arange(B), NF) -> sample s owns rows [s*50, s*50+50).
//
// Pipeline (2 launches):
//   k1 prep:  blocks 0..607 transpose W0->W0t [512][800], W1->W1t [512][416]
//             (bf16, n-major, zero-padded); blocks 608..: per-sample first+
//             second order -> fs, and emb -> x bf16 [16384][800].
//   k2 fused: one block per 64-sample panel, 512 threads (8 waves, 2Mx4N).
//             R1/R2 post-mortem: 2-barrier-per-plane schedule = m233's ~72%
//             stage+drain tax (58us at MfmaUtil 11%, nothing-bound).  This
//             version ports the T3/T4 counted-vmcnt discipline (m201):
//               phase 1 (x @ W0t): 3-deep plane buffers (32 chunks, 4/wave),
//                 stage p+2 at top, s_waitcnt vmcnt(8) + raw s_barrier ->
//                 loads for p+1/p+2 stay in flight ACROSS barriers.
//               phase 2 (h0p @ W1t): 3-deep single-plane buffers (28 chunks,
//                 waves 0-6 stage 4 each, wave 7 none -> uniform VMCNT(8)).
//                 R3 BUG FIX: pair buffers overflowed sS into h0p; single-
//                 plane 3-deep fits (43008 <= 49152 elems).
//             Phase 1->2 handoff: lgkmcnt(0)+raw barrier (publishes h0p
//             ds_writes WITHOUT draining prefetched planes).
//             T2 swizzle (rule #21 both-sides): global source slot ^=
//             (row>>1)&3 with linear LDS dest; fragment reads slot ^=
//             (l16>>1)&3 -> reads 2-way (free) instead of 8-way.
//             T5 setprio around MFMA clusters.  h0 stays in LDS.

#define BATCH 16384
#define NFLD  50
#define EK    16
#define DDIM  800   // NF*K  (= gemm1 K, exact, 25 planes)
#define HDIM  400
#define HPAD  416   // HDIM padded to mult of 32 (= gemm2 K, 13 planes)
#define NPAD  512   // W0t/W1t allocated rows

#define TB_W0 400
#define TB_W1 208
#define TBLK  (TB_W0 + TB_W1)
#define GBLK  (BATCH / 16)

#define MROWS 64             // samples per fused block
#define NCOLS 448            // gemm n-cols computed (28x16)
#define WCOLS 112            // n-cols per waveN
#define NFRAG 7              // 16-col frags per wave
#define P1    (DDIM / 32)    // 25 K-planes, phase 1
#define P2    (HPAD / 32)    // 13 K-planes, phase 2
#define H0S   424            // h0 LDS stride: 53x16B groups -> 2-way reads
#define SBUF  16384          // bf16 elems per phase-1 plane buffer (32 chunks)
#define SBUF2 14336          // bf16 elems per phase-2 plane buffer (28 chunks)

#define VMCNT(N) asm volatile("s_waitcnt vmcnt(" #N ")" ::: "memory")

typedef __attribute__((ext_vector_type(8))) __bf16 bf16x8;
typedef __attribute__((ext_vector_type(4))) float  f32x4;

typedef const __attribute__((address_space(1))) unsigned int* gas_u32p;
typedef __attribute__((address_space(3))) unsigned int*       las_u32p;

__device__ __forceinline__ void gld_lds16(const void* g, void* l) {
    __builtin_amdgcn_global_load_lds((gas_u32p)g, (las_u32p)l, 16, 0, 0);
}

__device__ __forceinline__ void bar() {
    // raw barrier (no vmcnt drain) with compile-time fences (rule #18/#21)
    __builtin_amdgcn_sched_barrier(0);
    __builtin_amdgcn_s_barrier();
    __builtin_amdgcn_sched_barrier(0);
}

// ---------------- k1: transpose (blocks < TBLK) + gather ----------------
__global__ __launch_bounds__(256) void prep_kernel(
    const float* __restrict__ W0, const float* __restrict__ W1,
    __hip_bfloat16* __restrict__ W0t, __hip_bfloat16* __restrict__ W1t,
    const int* __restrict__ feats, const float* __restrict__ values,
    const float* __restrict__ biasp, const float* __restrict__ weights,
    const float* __restrict__ embedding,
    float* __restrict__ fs, __hip_bfloat16* __restrict__ x)
{
    const int bid = blockIdx.x;
    if (bid < TBLK) {
        const int which = bid >= TB_W0;
        const int i  = which ? bid - TB_W0 : bid;
        const int nx = which ? 13 : 25;
        const int bx = i % nx, by = i / nx;
        const float* src = which ? W1 : W0;
        __hip_bfloat16* dst = which ? W1t : W0t;
        const int srcK = which ? HDIM : DDIM;
        const int dstCols = which ? HPAD : DDIM;

        __shared__ float tile[32][33];
        const int tx = threadIdx.x & 31, ty = threadIdx.x >> 5;
        const int k0 = bx * 32, n0 = by * 32;
#pragma unroll
        for (int r = 0; r < 4; ++r) {
            int k = k0 + ty + r * 8;
            int n = n0 + tx;
            float v = (k < srcK && n < HDIM) ? src[(long)k * HDIM + n] : 0.f;
            tile[ty + r * 8][tx] = v;
        }
        __syncthreads();
#pragma unroll
        for (int r = 0; r < 4; ++r) {
            int n = n0 + ty + r * 8;
            int k = k0 + tx;
            if (k < dstCols)
                dst[(long)n * dstCols + k] = __float2bfloat16(tile[tx][ty + r * 8]);
        }
        return;
    }

    const int wave = threadIdx.x >> 6;
    const int lane = threadIdx.x & 63;
    const int r    = lane >> 2, c = lane & 3;
    const int sbase = (bid - TBLK) * 16 + wave * 4;

    int   f[4] = {0, 0, 0, 0};
    float v[4] = {0.f, 0.f, 0.f, 0.f};
    float wsum[4] = {0.f, 0.f, 0.f, 0.f};
#pragma unroll
    for (int q = 0; q < 4; ++q) {
        const long base = (long)(sbase + q) * NFLD;
        if (lane < NFLD) {
            f[q] = feats[base + lane];
            v[q] = values[base + lane];
            wsum[q] = weights[f[q]] * v[q];
        }
    }

    int   fj[4][4]; float vj[4][4];
#pragma unroll
    for (int q = 0; q < 4; ++q)
#pragma unroll
        for (int p = 0; p < 4; ++p) {
            const int j = p * 16 + r;
            if (p < 3 || r < 2) {
                fj[q][p] = __shfl(f[q], j);
                vj[q][p] = __shfl(v[q], j);
            }
        }
    float4 e[4][4];
#pragma unroll
    for (int q = 0; q < 4; ++q)
#pragma unroll
        for (int p = 0; p < 4; ++p)
            if (p < 3 || r < 2)
                e[q][p] = *(const float4*)(embedding + (long)fj[q][p] * EK + c * 4);

#pragma unroll
    for (int q = 0; q < 4; ++q) {
        const int s = sbase + q;
        f32x4 s1 = {0.f, 0.f, 0.f, 0.f}, s2 = {0.f, 0.f, 0.f, 0.f};
#pragma unroll
        for (int p = 0; p < 4; ++p) {
            const int j = p * 16 + r;
            if (p < 3 || r < 2) {
                f32x4 ef = {e[q][p].x, e[q][p].y, e[q][p].z, e[q][p].w};
                f32x4 ev = ef * vj[q][p];
                s1 += ev;
                s2 += ev * ev;
                __hip_bfloat16 pk[4] = {
                    __float2bfloat16(e[q][p].x), __float2bfloat16(e[q][p].y),
                    __float2bfloat16(e[q][p].z), __float2bfloat16(e[q][p].w)};
                *(uint2*)&x[(long)s * DDIM + j * EK + c * 4] = *(uint2*)pk;
            }
        }
#pragma unroll
        for (int m = 4; m <= 32; m <<= 1) {
            s1.x += __shfl_xor(s1.x, m); s1.y += __shfl_xor(s1.y, m);
            s1.z += __shfl_xor(s1.z, m); s1.w += __shfl_xor(s1.w, m);
            s2.x += __shfl_xor(s2.x, m); s2.y += __shfl_xor(s2.y, m);
            s2.z += __shfl_xor(s2.z, m); s2.w += __shfl_xor(s2.w, m);
        }
        float t = (s1.x * s1.x - s2.x) + (s1.y * s1.y - s2.y)
                + (s1.z * s1.z - s2.z) + (s1.w * s1.w - s2.w);
        t += __shfl_xor(t, 1); t += __shfl_xor(t, 2);
        float w = wsum[q];
        w += __shfl_xor(w, 1);  w += __shfl_xor(w, 2);
        w += __shfl_xor(w, 4);  w += __shfl_xor(w, 8);
        w += __shfl_xor(w, 16); w += __shfl_xor(w, 32);
        if (lane == 0) fs[s] = w + 0.5f * t + biasp[0];
    }
}

// ---------------- k2: fused GEMM1 -> LDS h0 -> GEMM2 -> final ----------------
__global__ __launch_bounds__(512, 2) void fused_mlp_kernel(
    const __hip_bfloat16* __restrict__ x,
    const __hip_bfloat16* __restrict__ W0t, const __hip_bfloat16* __restrict__ W1t,
    const float* __restrict__ b0p, const float* __restrict__ b1p,
    const float* __restrict__ W2, const float* __restrict__ b2p,
    const float* __restrict__ fs, float* __restrict__ out)
{
    __shared__ __align__(16) __hip_bfloat16 sS[3 * SBUF];        // 96 KB staging
    __shared__ __align__(16) __hip_bfloat16 h0p[MROWS * H0S];    // 53 KB
    __shared__ float red[MROWS][4];                              // 1 KB

    const int tid  = threadIdx.x;
    const int wave = tid >> 6, lane = tid & 63;
    const int l16  = lane & 15, quad = lane >> 4;
    const int waveM = wave & 1, waveN = wave >> 1;
    const int m0 = blockIdx.x * MROWS;

    // staging lane geometry: chunk = 16 rows x 32 cols (1 KB);
    // lane -> row lane>>2, 16B slot lane&3; SOURCE slot pre-swizzled (rule #21)
    const int rl  = lane >> 2;
    const int swc = ((lane & 3) ^ ((lane >> 3) & 3)) * 8;   // = slot ^ ((row>>1)&3)
    // fragment-read slot swizzle: logical slot `quad` lives at quad ^ ((l16>>1)&3)
    const int qsw = (quad ^ ((l16 >> 1) & 3)) * 8;

    const float b0 = b0p[0];
    const float b1 = b1p[0];

    // ---- phase-1 staging: 32 chunks (A: 0..3 from x-panel, B: 4..31 W0t) ----
    auto stage1 = [&](int p, int b) {
        const int k0 = p * 32;
        __hip_bfloat16* dst = sS + b * SBUF;
#pragma unroll
        for (int c = 0; c < 4; ++c) {
            const int idx = wave * 4 + c;            // wave-uniform
            const __hip_bfloat16* src = (idx < 4)
                ? x   + (long)(m0 + idx * 16 + rl) * DDIM + k0 + swc
                : W0t + (long)((idx - 4) * 16 + rl) * DDIM + k0 + swc;
            gld_lds16(src, dst + idx * 512 + lane * 8);
        }
    };

    f32x4 acc[2][NFRAG] = {};
    auto compute1 = [&](int b) {
        const __hip_bfloat16* s = sS + b * SBUF;
        bf16x8 af[2], bfr[NFRAG];
#pragma unroll
        for (int i = 0; i < 2; ++i)
            af[i] = *(const bf16x8*)&s[(waveM * 2 + i) * 512 + l16 * 32 + qsw];
#pragma unroll
        for (int j = 0; j < NFRAG; ++j)
            bfr[j] = *(const bf16x8*)&s[(4 + waveN * NFRAG + j) * 512 + l16 * 32 + qsw];
        __builtin_amdgcn_s_setprio(1);
#pragma unroll
        for (int i = 0; i < 2; ++i)
#pragma unroll
            for (int j = 0; j < NFRAG; ++j)
                acc[i][j] = __builtin_amdgcn_mfma_f32_16x16x32_bf16(
                    af[i], bfr[j], acc[i][j], 0, 0, 0);
        __builtin_amdgcn_s_setprio(0);
    };

    // ---- phase 1: 3-deep counted-vmcnt pipeline (4 loads/wave/plane) ----
    stage1(0, 0);
    stage1(1, 1);
    for (int p = 0; p < P1; ++p) {
        if (p + 2 < P1) stage1(p + 2, (p + 2) % 3);
        if      (p + 2 < P1) { VMCNT(8); }
        else if (p + 1 < P1) { VMCNT(4); }
        else                 { VMCNT(0); }
        bar();                       // all waves' plane-p chunks landed
        compute1(p % 3);
        bar();                       // frees buf[p%3] for re-staging
    }

    // ---- h0 panel -> LDS, relu+b0; cols [400,416)->0; >=416 dropped ----
#pragma unroll
    for (int i = 0; i < 2; ++i)
#pragma unroll
        for (int j = 0; j < NFRAG; ++j) {
            const int col = waveN * WCOLS + j * 16 + l16;
            if (col < HPAD) {
#pragma unroll
                for (int r = 0; r < 4; ++r) {
                    const int row = waveM * 32 + i * 16 + quad * 4 + r;
                    float v = acc[i][j][r] + b0;
                    v = v > 0.f ? v : 0.f;
                    if (col >= HDIM) v = 0.f;
                    h0p[row * H0S + col] = __float2bfloat16(v);
                }
            }
        }

    // ---- phase-2 staging: 1 plane = 28 chunks of W1t; waves 0..6 x 4 ----
    auto stage2 = [&](int p, int b) {
        if (wave < 7) {
            const int k0 = p * 32;
#pragma unroll
            for (int c = 0; c < 4; ++c) {
                const int ch = wave * 4 + c;         // 0..27, wave-uniform
                gld_lds16(W1t + (long)(ch * 16 + rl) * HPAD + k0 + swc,
                          sS + b * SBUF2 + ch * 512 + lane * 8);
            }
        }
    };

    f32x4 acc2[2][NFRAG] = {};
    float w2v[NFRAG];
#pragma unroll
    for (int j = 0; j < NFRAG; ++j) {
        const int col = waveN * WCOLS + j * 16 + l16;
        w2v[j] = (col < HDIM) ? W2[col] : 0.f;
    }
    auto compute2 = [&](int p, int b) {
        const __hip_bfloat16* s = sS + b * SBUF2;
        bf16x8 af[2], bfr[NFRAG];
#pragma unroll
        for (int i = 0; i < 2; ++i)
            af[i] = *(const bf16x8*)&h0p[(waveM * 32 + i * 16 + l16) * H0S + p * 32 + quad * 8];
#pragma unroll
        for (int j = 0; j < NFRAG; ++j)
            bfr[j] = *(const bf16x8*)&s[(waveN * NFRAG + j) * 512 + l16 * 32 + qsw];
        __builtin_amdgcn_s_setprio(1);
#pragma unroll
        for (int i = 0; i < 2; ++i)
#pragma unroll
            for (int j = 0; j < NFRAG; ++j)
                acc2[i][j] = __builtin_amdgcn_mfma_f32_16x16x32_bf16(
                    af[i], bfr[j], acc2[i][j], 0, 0, 0);
        __builtin_amdgcn_s_setprio(0);
    };

    // prologue: issue planes 0,1 (safe: final phase-1 bar() freed all of sS);
    // publish h0p with lgkmcnt-only drain so prefetch stays in flight
    stage2(0, 0);
    stage2(1, 1);
    asm volatile("s_waitcnt lgkmcnt(0)" ::: "memory");
    bar();

    // ---- phase 2: 3-deep counted-vmcnt pipeline over 13 planes ----
    for (int p = 0; p < P2; ++p) {
        if (p + 2 < P2) stage2(p + 2, (p + 2) % 3);
        if      (p + 2 < P2) { VMCNT(8); }   // wave 7: trivially satisfied
        else if (p + 1 < P2) { VMCNT(4); }
        else                 { VMCNT(0); }
        bar();
        compute2(p, p % 3);
        bar();
    }

    // ---- epilogue: relu(acc2+b1) . W2, lane reduce, cross-wave, sigmoid ----
#pragma unroll
    for (int i = 0; i < 2; ++i)
#pragma unroll
        for (int r = 0; r < 4; ++r) {
            float ps = 0.f;
#pragma unroll
            for (int j = 0; j < NFRAG; ++j) {
                float v = acc2[i][j][r] + b1;
                v = v > 0.f ? v : 0.f;
                ps += v * w2v[j];
            }
            ps += __shfl_xor(ps, 1); ps += __shfl_xor(ps, 2);
            ps += __shfl_xor(ps, 4); ps += __shfl_xor(ps, 8);
            if (l16 == 0)
                red[waveM * 32 + i * 16 + quad * 4 + r][waveN] = ps;
        }
    __syncthreads();

    if (tid < MROWS) {
        const float s = (red[tid][0] + red[tid][1]) + (red[tid][2] + red[tid][3]);
        float hv = s + b2p[0];
        hv = hv > 0.f ? hv : 0.f;
        const float z = fs[m0 + tid] + hv;
        out[m0 + tid] = 1.f / (1.f + __expf(-z));
    }
}

extern "C" void kernel_launch(void* const* d_in, const int* in_sizes, int n_in,
                              void* d_out, int out_size, void* d_ws, size_t ws_size,
                              hipStream_t stream)
{
    const int*   feats     = (const int*)d_in[1];
    const float* values    = (const float*)d_in[2];
    const float* bias      = (const float*)d_in[3];
    const float* weights   = (const float*)d_in[4];
    const float* embedding = (const float*)d_in[5];
    const float* W0 = (const float*)d_in[6];
    const float* b0 = (const float*)d_in[7];
    const float* W1 = (const float*)d_in[8];
    const float* b1 = (const float*)d_in[9];
    const float* W2 = (const float*)d_in[10];
    const float* b2 = (const float*)d_in[11];

    char* ws = (char*)d_ws;
    size_t off = 0;
    auto alloc = [&](size_t bytes) {
        void* p = ws + off;
        off += (bytes + 255) & ~(size_t)255;
        return p;
    };
    float*          fs   = (float*)alloc((size_t)BATCH * 4);
    __hip_bfloat16* x    = (__hip_bfloat16*)alloc((size_t)BATCH * DDIM * 2);
    __hip_bfloat16* W0t  = (__hip_bfloat16*)alloc((size_t)NPAD * DDIM * 2);
    __hip_bfloat16* W1t  = (__hip_bfloat16*)alloc((size_t)NPAD * HPAD * 2);
    (void)ws_size; (void)in_sizes; (void)n_in; (void)out_size;

    prep_kernel<<<dim3(TBLK + GBLK), 256, 0, stream>>>(
        W0, W1, W0t, W1t, feats, values, bias, weights, embedding, fs, x);
    fused_mlp_kernel<<<dim3(BATCH / MROWS), 512, 0, stream>>>(
        x, W0t, W1t, b0, b1, W2, b2, fs, (float*)d_out);
}

// Round 6
// 166.118 us; speedup vs baseline: 1.1260x; 1.0718x over previous
//
#include <hip/hip_runtime.h>
#include <hip/hip_bf16.h>

// DeepFM on MI355X. B=16384, NF=50, K=16, V=1e6, H=400, d=800.
// index = repeat(arange(B), NF) -> sample s owns rows [s*50, s*50+50).
//
// Timed-region decomposition (R4): ~123us = 3x 256-MiB harness poison fills
// (fixed floor) + prep ~14us + fused (this file's target, R4 = 41us).
//
// R5 post-mortem: BK=64 pair buffers need 64 KB each (2-deep = 128 KB +
// h0p 53 KB > 160 KB LDS) -- the R5 submission compressed strides and
// self-clobbered.  Reverted.  This round tests the SAME barrier-tax theory
// legally: ONE barrier per K-plane instead of two, same 3-deep rotating
// buffers (safety: at bar(p) all waves finished compute(p-1)'s ds_reads,
// so staging into buf (p+2)%3 == (p-1)%3 after bar(p) is race-free;
// VMCNT(4) before bar(p) ensures plane p landed with 2 planes in flight).
// Barrier count 78 -> ~41.  Everything else is R4-identical.
//
//   k1 prep:  blocks 0..607 transpose W0->W0t [512][800], W1->W1t [512][416]
//             (bf16, n-major, zero-padded); blocks 608..: per-sample first+
//             second order -> fs, emb -> x bf16 [16384][800].
//   k2 fused: one block per 64-sample panel, 512 threads (8 waves, 2Mx4N):
//             phase 1: h0 = relu(x @ W0t + b0) -> LDS [64][424] bf16,
//               25 BK=32 planes, 3-deep, 1 bar/plane, VMCNT(4).
//             phase 2: h1 = relu(h0 @ W1t + b1) . W2, 13 planes, 3-deep,
//               1 bar/plane, VMCNT(4); out = sigmoid(fs + relu(sum + b2)).
//             T2 both-sides swizzle (source slot ^ (row>>1)&3, read slot ^
//             (l16>>1)&3) -> 2-way LDS reads.  T5 setprio around MFMA.

#define BATCH 16384
#define NFLD  50
#define EK    16
#define DDIM  800   // NF*K  (= gemm1 K, exact, 25 planes)
#define HDIM  400
#define HPAD  416   // gemm2 K (13 planes)
#define NPAD  512   // W0t/W1t allocated rows

#define TB_W0 400            // 25 k-tiles x 16 n-tiles for W0 transpose
#define TB_W1 208            // 13 k-tiles x 16 n-tiles for W1 transpose
#define TBLK  (TB_W0 + TB_W1)
#define GBLK  (BATCH / 16)

#define MROWS 64             // samples per fused block
#define NCOLS 448            // gemm n-cols computed (28x16)
#define WCOLS 112            // n-cols per waveN
#define NFRAG 7              // 16-col frags per wave
#define P1    (DDIM / 32)    // 25 K-planes, phase 1
#define P2    (HPAD / 32)    // 13 K-planes, phase 2
#define H0S   424            // h0 LDS stride: 848B rows -> 2-way af reads

// LDS byte offsets
#define PH1B(b) ((b) * 32768)          // 3 plane buffers (A 4KB + B 28KB)
#define PH2B(b) ((b) * 28672)          // 3 plane buffers (B only, 28KB)
#define H0OFF   98304                  // h0p: 64*424*2 = 54272 B
#define REDOFF  152576                 // red: 64*4*4 = 1024 B
#define LDSSZ   153600                 // 150 KB (same as R4)

#define VMCNT(N) asm volatile("s_waitcnt vmcnt(" #N ")" ::: "memory")

typedef __attribute__((ext_vector_type(8))) __bf16 bf16x8;
typedef __attribute__((ext_vector_type(4))) float  f32x4;

typedef const __attribute__((address_space(1))) unsigned int* gas_u32p;
typedef __attribute__((address_space(3))) unsigned int*       las_u32p;

__device__ __forceinline__ void gld_lds16(const void* g, void* l) {
    __builtin_amdgcn_global_load_lds((gas_u32p)g, (las_u32p)l, 16, 0, 0);
}

__device__ __forceinline__ void bar() {
    // raw barrier (no vmcnt drain) with compile-time fences (rule #18/#21)
    __builtin_amdgcn_sched_barrier(0);
    __builtin_amdgcn_s_barrier();
    __builtin_amdgcn_sched_barrier(0);
}

// ---------------- k1: transpose (blocks < TBLK) + gather ----------------
__global__ __launch_bounds__(256) void prep_kernel(
    const float* __restrict__ W0, const float* __restrict__ W1,
    __hip_bfloat16* __restrict__ W0t, __hip_bfloat16* __restrict__ W1t,
    const int* __restrict__ feats, const float* __restrict__ values,
    const float* __restrict__ biasp, const float* __restrict__ weights,
    const float* __restrict__ embedding,
    float* __restrict__ fs, __hip_bfloat16* __restrict__ x)
{
    const int bid = blockIdx.x;
    if (bid < TBLK) {
        const int which = bid >= TB_W0;
        const int i  = which ? bid - TB_W0 : bid;
        const int nx = which ? 13 : 25;                  // k-tiles
        const int bx = i % nx, by = i / nx;
        const float* src = which ? W1 : W0;
        __hip_bfloat16* dst = which ? W1t : W0t;
        const int srcK = which ? HDIM : DDIM;            // source rows (k)
        const int dstCols = which ? HPAD : DDIM;

        __shared__ float tile[32][33];
        const int tx = threadIdx.x & 31, ty = threadIdx.x >> 5;
        const int k0 = bx * 32, n0 = by * 32;
#pragma unroll
        for (int r = 0; r < 4; ++r) {
            int k = k0 + ty + r * 8;
            int n = n0 + tx;
            float v = (k < srcK && n < HDIM) ? src[(long)k * HDIM + n] : 0.f;
            tile[ty + r * 8][tx] = v;
        }
        __syncthreads();
#pragma unroll
        for (int r = 0; r < 4; ++r) {
            int n = n0 + ty + r * 8;   // dst row
            int k = k0 + tx;           // dst col
            if (k < dstCols)
                dst[(long)n * dstCols + k] = __float2bfloat16(tile[tx][ty + r * 8]);
        }
        return;
    }

    const int wave = threadIdx.x >> 6;
    const int lane = threadIdx.x & 63;
    const int r    = lane >> 2, c = lane & 3;
    const int sbase = (bid - TBLK) * 16 + wave * 4;

    int   f[4] = {0, 0, 0, 0};
    float v[4] = {0.f, 0.f, 0.f, 0.f};
    float wsum[4] = {0.f, 0.f, 0.f, 0.f};
#pragma unroll
    for (int q = 0; q < 4; ++q) {
        const long base = (long)(sbase + q) * NFLD;
        if (lane < NFLD) {
            f[q] = feats[base + lane];
            v[q] = values[base + lane];
            wsum[q] = weights[f[q]] * v[q];
        }
    }

    int   fj[4][4]; float vj[4][4];
#pragma unroll
    for (int q = 0; q < 4; ++q)
#pragma unroll
        for (int p = 0; p < 4; ++p) {
            const int j = p * 16 + r;
            if (p < 3 || r < 2) {
                fj[q][p] = __shfl(f[q], j);
                vj[q][p] = __shfl(v[q], j);
            }
        }
    float4 e[4][4];
#pragma unroll
    for (int q = 0; q < 4; ++q)
#pragma unroll
        for (int p = 0; p < 4; ++p)
            if (p < 3 || r < 2)
                e[q][p] = *(const float4*)(embedding + (long)fj[q][p] * EK + c * 4);

#pragma unroll
    for (int q = 0; q < 4; ++q) {
        const int s = sbase + q;
        f32x4 s1 = {0.f, 0.f, 0.f, 0.f}, s2 = {0.f, 0.f, 0.f, 0.f};
#pragma unroll
        for (int p = 0; p < 4; ++p) {
            const int j = p * 16 + r;
            if (p < 3 || r < 2) {
                f32x4 ef = {e[q][p].x, e[q][p].y, e[q][p].z, e[q][p].w};
                f32x4 ev = ef * vj[q][p];
                s1 += ev;
                s2 += ev * ev;
                __hip_bfloat16 pk[4] = {
                    __float2bfloat16(e[q][p].x), __float2bfloat16(e[q][p].y),
                    __float2bfloat16(e[q][p].z), __float2bfloat16(e[q][p].w)};
                *(uint2*)&x[(long)s * DDIM + j * EK + c * 4] = *(uint2*)pk;
            }
        }
#pragma unroll
        for (int m = 4; m <= 32; m <<= 1) {
            s1.x += __shfl_xor(s1.x, m); s1.y += __shfl_xor(s1.y, m);
            s1.z += __shfl_xor(s1.z, m); s1.w += __shfl_xor(s1.w, m);
            s2.x += __shfl_xor(s2.x, m); s2.y += __shfl_xor(s2.y, m);
            s2.z += __shfl_xor(s2.z, m); s2.w += __shfl_xor(s2.w, m);
        }
        float t = (s1.x * s1.x - s2.x) + (s1.y * s1.y - s2.y)
                + (s1.z * s1.z - s2.z) + (s1.w * s1.w - s2.w);
        t += __shfl_xor(t, 1); t += __shfl_xor(t, 2);
        float w = wsum[q];
        w += __shfl_xor(w, 1);  w += __shfl_xor(w, 2);
        w += __shfl_xor(w, 4);  w += __shfl_xor(w, 8);
        w += __shfl_xor(w, 16); w += __shfl_xor(w, 32);
        if (lane == 0) fs[s] = w + 0.5f * t + biasp[0];
    }
}

// ---------------- k2: fused GEMM1 -> LDS h0 -> GEMM2 -> final ----------------
__global__ __launch_bounds__(512, 2) void fused_mlp_kernel(
    const __hip_bfloat16* __restrict__ x,
    const __hip_bfloat16* __restrict__ W0t, const __hip_bfloat16* __restrict__ W1t,
    const float* __restrict__ b0p, const float* __restrict__ b1p,
    const float* __restrict__ W2, const float* __restrict__ b2p,
    const float* __restrict__ fs, float* __restrict__ out)
{
    __shared__ __align__(16) char lds[LDSSZ];
    __hip_bfloat16* h0p = (__hip_bfloat16*)(lds + H0OFF);
    float*          red = (float*)(lds + REDOFF);

    const int tid  = threadIdx.x;
    const int wave = tid >> 6, lane = tid & 63;
    const int l16  = lane & 15, quad = lane >> 4;
    const int waveM = wave & 1, waveN = wave >> 1;
    const int m0 = blockIdx.x * MROWS;

    // staging lane geometry: chunk = 16 rows x 32 cols (1 KB);
    // lane -> row lane>>2, 16B slot lane&3; SOURCE slot pre-swizzled (rule #21)
    const int rl  = lane >> 2;
    const int swc = ((lane & 3) ^ ((lane >> 3) & 3)) * 8;   // = slot ^ ((row>>1)&3)
    // fragment-read slot swizzle: logical slot `quad` lives at quad ^ ((l16>>1)&3)
    const int qsw = (quad ^ ((l16 >> 1) & 3)) * 8;

    const float b0 = b0p[0];
    const float b1 = b1p[0];

    // ---- phase-1 staging: 1 plane = 32 chunks (A: 0..3 x-rows, B: 4..31
    // W0t rows), 4 chunks per wave ----
    auto stage1 = [&](int p, int b) {
        const int k0 = p * 32;
        char* dst = lds + PH1B(b);
#pragma unroll
        for (int c = 0; c < 4; ++c) {
            const int idx = wave * 4 + c;            // wave-uniform
            const __hip_bfloat16* src = (idx < 4)
                ? x   + (long)(m0 + idx * 16 + rl) * DDIM + k0 + swc
                : W0t + (long)((idx - 4) * 16 + rl) * DDIM + k0 + swc;
            gld_lds16(src, dst + idx * 1024 + lane * 16);
        }
    };

    f32x4 acc[2][NFRAG] = {};
    auto compute1 = [&](int b) {
        const __hip_bfloat16* s = (const __hip_bfloat16*)(lds + PH1B(b));
        bf16x8 af[2], bfr[NFRAG];
#pragma unroll
        for (int i = 0; i < 2; ++i)
            af[i] = *(const bf16x8*)&s[(waveM * 2 + i) * 512 + l16 * 32 + qsw];
#pragma unroll
        for (int j = 0; j < NFRAG; ++j)
            bfr[j] = *(const bf16x8*)&s[(4 + waveN * NFRAG + j) * 512 + l16 * 32 + qsw];
        __builtin_amdgcn_s_setprio(1);
#pragma unroll
        for (int i = 0; i < 2; ++i)
#pragma unroll
            for (int j = 0; j < NFRAG; ++j)
                acc[i][j] = __builtin_amdgcn_mfma_f32_16x16x32_bf16(
                    af[i], bfr[j], acc[i][j], 0, 0, 0);
        __builtin_amdgcn_s_setprio(0);
    };

    // ---- phase 1: 25 planes, 3-deep, ONE barrier per plane ----
    // invariant at bar(p): plane p landed (VMCNT(4), 2 planes in flight);
    // all waves finished compute(p-1) -> staging buf (p+2)%3 == (p-1)%3
    // after the bar is race-free.
    stage1(0, 0);
    stage1(1, 1);
    for (int p = 0; p < P1; ++p) {
        if (p + 1 < P1) { VMCNT(4); } else { VMCNT(0); }
        bar();
        if (p + 2 < P1) stage1(p + 2, (p + 2) % 3);
        compute1(p % 3);
    }
    bar();   // all compute1 ds_reads done before phase-2 staging overwrites

    // prologue for phase 2: issue planes 0,1 ASAP (overlap with h0p writes)
    auto stage2 = [&](int p, int b) {
        if (wave < 7) {
            const int k0 = p * 32;
#pragma unroll
            for (int c = 0; c < 4; ++c) {
                const int ch = wave * 4 + c;         // 0..27, wave-uniform
                gld_lds16(W1t + (long)(ch * 16 + rl) * HPAD + k0 + swc,
                          lds + PH2B(b) + ch * 1024 + lane * 16);
            }
        }
    };
    stage2(0, 0);
    stage2(1, 1);

    // ---- h0 panel -> LDS, relu+b0; cols [400,416)->0; >=416 dropped ----
#pragma unroll
    for (int i = 0; i < 2; ++i)
#pragma unroll
        for (int j = 0; j < NFRAG; ++j) {
            const int col = waveN * WCOLS + j * 16 + l16;
            if (col < HPAD) {
#pragma unroll
                for (int r = 0; r < 4; ++r) {
                    const int row = waveM * 32 + i * 16 + quad * 4 + r;
                    float v = acc[i][j][r] + b0;
                    v = v > 0.f ? v : 0.f;
                    if (col >= HDIM) v = 0.f;
                    h0p[row * H0S + col] = __float2bfloat16(v);
                }
            }
        }

    f32x4 acc2[2][NFRAG] = {};
    float w2v[NFRAG];
#pragma unroll
    for (int j = 0; j < NFRAG; ++j) {
        const int col = waveN * WCOLS + j * 16 + l16;
        w2v[j] = (col < HDIM) ? W2[col] : 0.f;
    }
    auto compute2 = [&](int p, int b) {
        const __hip_bfloat16* s = (const __hip_bfloat16*)(lds + PH2B(b));
        bf16x8 af[2], bfr[NFRAG];
#pragma unroll
        for (int i = 0; i < 2; ++i)
            af[i] = *(const bf16x8*)&h0p[(waveM * 32 + i * 16 + l16) * H0S + p * 32 + quad * 8];
#pragma unroll
        for (int j = 0; j < NFRAG; ++j)
            bfr[j] = *(const bf16x8*)&s[(waveN * NFRAG + j) * 512 + l16 * 32 + qsw];
        __builtin_amdgcn_s_setprio(1);
#pragma unroll
        for (int i = 0; i < 2; ++i)
#pragma unroll
            for (int j = 0; j < NFRAG; ++j)
                acc2[i][j] = __builtin_amdgcn_mfma_f32_16x16x32_bf16(
                    af[i], bfr[j], acc2[i][j], 0, 0, 0);
        __builtin_amdgcn_s_setprio(0);
    };

    // publish h0p (ds_writes) WITHOUT draining the in-flight stage2 DMA
    asm volatile("s_waitcnt lgkmcnt(0)" ::: "memory");
    bar();

    // ---- phase 2: 13 planes, 3-deep, ONE barrier per plane ----
    for (int p = 0; p < P2; ++p) {
        if (p + 1 < P2) { VMCNT(4); } else { VMCNT(0); }   // wave7: trivial
        bar();
        if (p + 2 < P2) stage2(p + 2, (p + 2) % 3);
        compute2(p, p % 3);
    }

    // ---- epilogue: relu(acc2+b1) . W2, lane reduce, cross-wave, sigmoid ----
#pragma unroll
    for (int i = 0; i < 2; ++i)
#pragma unroll
        for (int r = 0; r < 4; ++r) {
            float ps = 0.f;
#pragma unroll
            for (int j = 0; j < NFRAG; ++j) {
                float v = acc2[i][j][r] + b1;
                v = v > 0.f ? v : 0.f;
                ps += v * w2v[j];
            }
            ps += __shfl_xor(ps, 1); ps += __shfl_xor(ps, 2);
            ps += __shfl_xor(ps, 4); ps += __shfl_xor(ps, 8);
            if (l16 == 0)
                red[(waveM * 32 + i * 16 + quad * 4 + r) * 4 + waveN] = ps;
        }
    __syncthreads();

    if (tid < MROWS) {
        const float4 rr = *(const float4*)&red[tid * 4];
        const float s = (rr.x + rr.y) + (rr.z + rr.w);
        float hv = s + b2p[0];
        hv = hv > 0.f ? hv : 0.f;
        const float z = fs[m0 + tid] + hv;
        out[m0 + tid] = 1.f / (1.f + __expf(-z));
    }
}

extern "C" void kernel_launch(void* const* d_in, const int* in_sizes, int n_in,
                              void* d_out, int out_size, void* d_ws, size_t ws_size,
                              hipStream_t stream)
{
    const int*   feats     = (const int*)d_in[1];
    const float* values    = (const float*)d_in[2];
    const float* bias      = (const float*)d_in[3];
    const float* weights   = (const float*)d_in[4];
    const float* embedding = (const float*)d_in[5];
    const float* W0 = (const float*)d_in[6];
    const float* b0 = (const float*)d_in[7];
    const float* W1 = (const float*)d_in[8];
    const float* b1 = (const float*)d_in[9];
    const float* W2 = (const float*)d_in[10];
    const float* b2 = (const float*)d_in[11];

    char* ws = (char*)d_ws;
    size_t off = 0;
    auto alloc = [&](size_t bytes) {
        void* p = ws + off;
        off += (bytes + 255) & ~(size_t)255;
        return p;
    };
    float*          fs   = (float*)alloc((size_t)BATCH * 4);
    __hip_bfloat16* x    = (__hip_bfloat16*)alloc((size_t)BATCH * DDIM * 2);
    __hip_bfloat16* W0t  = (__hip_bfloat16*)alloc((size_t)NPAD * DDIM * 2);
    __hip_bfloat16* W1t  = (__hip_bfloat16*)alloc((size_t)NPAD * HPAD * 2);
    (void)ws_size; (void)in_sizes; (void)n_in; (void)out_size;

    prep_kernel<<<dim3(TBLK + GBLK), 256, 0, stream>>>(
        W0, W1, W0t, W1t, feats, values, bias, weights, embedding, fs, x);
    fused_mlp_kernel<<<dim3(BATCH / MROWS), 512, 0, stream>>>(
        x, W0t, W1t, b0, b1, W2, b2, fs, (float*)d_out);
}